// Round 28
// baseline (2407.997 us; speedup 1.0000x reference)
//
#include <hip/hip_runtime.h>
#include <math.h>

#define T_DIM 1024
#define B_DIM 256
#define D_DIM 32
#define H_DIM 128

// Bit-faithful XLA-CPU / Eigen fast-tanh, WITH-FMA variant — FROZEN.
// Verified bit-exact vs the harness reference (absmax 0.0, rounds 15-27).
__device__ __forceinline__ float xla_tanh_fma_f32(float x) {
  const float plim = 7.99881172180175781f;
  float xc = fminf(fmaxf(x, -plim), plim);
  float x2 = __fmul_rn(xc, xc);
  float p;
  p = fmaf(x2, -2.76076847742355e-16f, 2.00018790482477e-13f);
  p = fmaf(x2, p, -8.60467152213735e-11f);
  p = fmaf(x2, p,  5.12229709037114e-08f);
  p = fmaf(x2, p,  1.48572235717979e-05f);
  p = fmaf(x2, p,  6.37261928875436e-04f);
  p = fmaf(x2, p,  4.89352455891786e-03f);
  float num = __fmul_rn(xc, p);
  float q;
  q = fmaf(x2, 1.19825839466702e-06f, 1.18534705686654e-04f);
  q = fmaf(x2, q, 2.26843463243900e-03f);
  q = fmaf(x2, q, 4.89352518554385e-03f);
  float r = __fdiv_rn(num, q);
  return (fabsf(x) < 0.0004f) ? x : r;
}

// 1 LANE PER OUTPUT (no systolic redundancy — R26's 2-way split doubled
// FMA issue as the price of fitting weights in regs). The register-cap
// problem (R17-20: allocator refuses >~96 live) is solved by SOURCING most
// weights from LDS instead: W_h rows 32..127 and all W_in live in LDS as
// [k][j] (per-lane b32 reads hit bank j%32 -> 2 lanes/bank = free); only
// W_h rows 0..31 stay in VGPRs. Live set ~90 regs. Same fmaf stream ->
// bit-exact. 128 threads (2 waves); idle SIMDs are fine: the serial
// 128-FMA chain is the latency floor, and s1/x-load latency hides under
// it (s1 joins only at the end: a = (s1+s2)+b).
__global__ __launch_bounds__(128, 1) void diffeq_kernel(
    const float* __restrict__ x, const float* __restrict__ state,
    const float* __restrict__ W_in, const float* __restrict__ W_h,
    const float* __restrict__ bias, float* __restrict__ out) {
  __shared__ float WHH[96 * H_DIM];          // W_h rows 32..127 (48 KB)
  __shared__ float WI[D_DIM * H_DIM];        // W_in rows 0..31  (16 KB)
  __shared__ __align__(16) float h0[H_DIM];
  __shared__ __align__(16) float h1[H_DIM];

  const int b = blockIdx.x;
  const int j = threadIdx.x;                 // output index 0..127

  // ---- stage weights into LDS (coalesced: lane j writes column j) ----
  for (int r = 0; r < 96; ++r) WHH[r * H_DIM + j] = W_h[(32 + r) * H_DIM + j];
#pragma unroll
  for (int r = 0; r < D_DIM; ++r) WI[r * H_DIM + j] = W_in[r * H_DIM + j];

  // ---- W_h rows 0..31, column j, in 32 VGPRs ----
  float whlo[32];
#pragma unroll
  for (int k = 0; k < 32; ++k) whlo[k] = W_h[k * H_DIM + j];
  const float bj = bias[j];

  float hown = state[(size_t)b * H_DIM + j];
  h0[j] = hown;
  __syncthreads();

  const size_t out_row = (size_t)b * H_DIM + j;
  const float4* xg4 = reinterpret_cast<const float4*>(x + (size_t)b * D_DIM);
  const int xs4 = B_DIM * D_DIM / 4;         // float4 stride per t

#define STEP(HRD, HWR, TIDX) { \
    /* x row: 8 b128 global loads (same addr all lanes; L2/L3-resident). \
       Latency hides under the 512-cyc s2 chain (s1 joins at the end). */ \
    const float4* xp = xg4 + (size_t)(TIDX) * xs4; \
    float4 x0 = xp[0], x1 = xp[1], x2_ = xp[2], x3 = xp[3]; \
    float4 x4 = xp[4], x5 = xp[5], x6 = xp[6], x7 = xp[7]; \
    const float4* hq4 = reinterpret_cast<const float4*>(HRD); \
    /* s2: k=0..31 from whlo regs, k=32..127 from WHH LDS (bank-free). */ \
    float s2 = 0.f; \
    _Pragma("unroll") \
    for (int q = 0; q < 8; ++q) { \
      float4 h4 = hq4[q];                       /* broadcast read */ \
      s2 = fmaf(h4.x, whlo[4 * q + 0], s2); \
      s2 = fmaf(h4.y, whlo[4 * q + 1], s2); \
      s2 = fmaf(h4.z, whlo[4 * q + 2], s2); \
      s2 = fmaf(h4.w, whlo[4 * q + 3], s2); \
    } \
    _Pragma("unroll") \
    for (int q = 8; q < 32; ++q) { \
      float4 h4 = hq4[q];                       /* broadcast read */ \
      s2 = fmaf(h4.x, WHH[(4 * q - 32 + 0) * H_DIM + j], s2); \
      s2 = fmaf(h4.y, WHH[(4 * q - 32 + 1) * H_DIM + j], s2); \
      s2 = fmaf(h4.z, WHH[(4 * q - 32 + 2) * H_DIM + j], s2); \
      s2 = fmaf(h4.w, WHH[(4 * q - 32 + 3) * H_DIM + j], s2); \
    } \
    /* s1: independent 32-FMA chain; x from regs, W_in from LDS. */ \
    float s1 = 0.f; \
    s1 = fmaf(x0.x, WI[0  * H_DIM + j], s1); s1 = fmaf(x0.y, WI[1  * H_DIM + j], s1); \
    s1 = fmaf(x0.z, WI[2  * H_DIM + j], s1); s1 = fmaf(x0.w, WI[3  * H_DIM + j], s1); \
    s1 = fmaf(x1.x, WI[4  * H_DIM + j], s1); s1 = fmaf(x1.y, WI[5  * H_DIM + j], s1); \
    s1 = fmaf(x1.z, WI[6  * H_DIM + j], s1); s1 = fmaf(x1.w, WI[7  * H_DIM + j], s1); \
    s1 = fmaf(x2_.x, WI[8 * H_DIM + j], s1); s1 = fmaf(x2_.y, WI[9  * H_DIM + j], s1); \
    s1 = fmaf(x2_.z, WI[10 * H_DIM + j], s1); s1 = fmaf(x2_.w, WI[11 * H_DIM + j], s1); \
    s1 = fmaf(x3.x, WI[12 * H_DIM + j], s1); s1 = fmaf(x3.y, WI[13 * H_DIM + j], s1); \
    s1 = fmaf(x3.z, WI[14 * H_DIM + j], s1); s1 = fmaf(x3.w, WI[15 * H_DIM + j], s1); \
    s1 = fmaf(x4.x, WI[16 * H_DIM + j], s1); s1 = fmaf(x4.y, WI[17 * H_DIM + j], s1); \
    s1 = fmaf(x4.z, WI[18 * H_DIM + j], s1); s1 = fmaf(x4.w, WI[19 * H_DIM + j], s1); \
    s1 = fmaf(x5.x, WI[20 * H_DIM + j], s1); s1 = fmaf(x5.y, WI[21 * H_DIM + j], s1); \
    s1 = fmaf(x5.z, WI[22 * H_DIM + j], s1); s1 = fmaf(x5.w, WI[23 * H_DIM + j], s1); \
    s1 = fmaf(x6.x, WI[24 * H_DIM + j], s1); s1 = fmaf(x6.y, WI[25 * H_DIM + j], s1); \
    s1 = fmaf(x6.z, WI[26 * H_DIM + j], s1); s1 = fmaf(x6.w, WI[27 * H_DIM + j], s1); \
    s1 = fmaf(x7.x, WI[28 * H_DIM + j], s1); s1 = fmaf(x7.y, WI[29 * H_DIM + j], s1); \
    s1 = fmaf(x7.z, WI[30 * H_DIM + j], s1); s1 = fmaf(x7.w, WI[31 * H_DIM + j], s1); \
    float a  = __fadd_rn(__fadd_rn(s1, s2), bj); \
    float th = xla_tanh_fma_f32(a); \
    float hv = __fadd_rn(hown, th); \
    (HWR)[j] = hv; \
    hown = hv; \
    __syncthreads(); \
    /* store AFTER barrier: vmcnt drain hides under the next step. */ \
    out[(size_t)(TIDX) * (B_DIM * H_DIM) + out_row] = hv; \
  }

  for (int t = 0; t < T_DIM; t += 2) {
    STEP(h0, h1, t)        // even: h0 -> h1
    STEP(h1, h0, t + 1)    // odd:  h1 -> h0
  }

  // final_state = h after last step (== outputs[T-1])
  out[(size_t)T_DIM * B_DIM * H_DIM + out_row] = hown;
}

extern "C" void kernel_launch(void* const* d_in, const int* in_sizes, int n_in,
                              void* d_out, int out_size, void* d_ws, size_t ws_size,
                              hipStream_t stream) {
  const float* x     = (const float*)d_in[0];
  const float* state = (const float*)d_in[1];
  const float* W_in  = (const float*)d_in[2];
  const float* W_h   = (const float*)d_in[3];
  const float* bias  = (const float*)d_in[4];
  float* out = (float*)d_out;

  diffeq_kernel<<<B_DIM, 128, 0, stream>>>(x, state, W_in, W_h, bias, out);
}

// Round 29
// 789.402 us; speedup vs baseline: 3.0504x; 3.0504x over previous
//
#include <hip/hip_runtime.h>
#include <math.h>

#define T_DIM 1024
#define B_DIM 256
#define D_DIM 32
#define H_DIM 128
#define HP 68   // float stride between the two 64-float h halves (17 quads)
#define BH (B_DIM * H_DIM)

// Bit-faithful XLA-CPU / Eigen fast-tanh, WITH-FMA variant — FROZEN.
// Verified bit-exact vs the harness reference (absmax 0.0, rounds 15-28).
__device__ __forceinline__ float xla_tanh_fma_f32(float x) {
  const float plim = 7.99881172180175781f;
  float xc = fminf(fmaxf(x, -plim), plim);
  float x2 = __fmul_rn(xc, xc);
  float p;
  p = fmaf(x2, -2.76076847742355e-16f, 2.00018790482477e-13f);
  p = fmaf(x2, p, -8.60467152213735e-11f);
  p = fmaf(x2, p,  5.12229709037114e-08f);
  p = fmaf(x2, p,  1.48572235717979e-05f);
  p = fmaf(x2, p,  6.37261928875436e-04f);
  p = fmaf(x2, p,  4.89352455891786e-03f);
  float num = __fmul_rn(xc, p);
  float q;
  q = fmaf(x2, 1.19825839466702e-06f, 1.18534705686654e-04f);
  q = fmaf(x2, q, 2.26843463243900e-03f);
  q = fmaf(x2, q, 4.89352518554385e-03f);
  float r = __fdiv_rn(num, q);
  return (fabsf(x) < 0.0004f) ? x : r;
}

// Accumulator hop: lane L receives lane L-1 (row_shr:1, exact bit copy).
__device__ __forceinline__ float dpp_shr1(float v) {
  return __int_as_float(__builtin_amdgcn_update_dpp(
      __float_as_int(v), __float_as_int(v), 0x111, 0xf, 0xf, false));
}

// R26 (2-lane systolic, HP=68 bank-disjoint h, conflict-free) + issue trims:
//  - pointer-increment addressing for x prefetch and out store (removes
//    per-step 64-bit t*stride multiplies — ~150 inst/step of overhead)
//  - x prefetch issued at step top (full step of latency slack)
//  - s1 (register-only) first in each round: covers the h b128 read latency
// Weights stay in VGPRs (R28 proved chain operands from LDS stall 4x);
// h comes from LDS broadcast reads. Arithmetic stream unchanged (bit-exact).
__global__ __launch_bounds__(256, 1) void diffeq_kernel(
    const float* __restrict__ x, const float* __restrict__ state,
    const float* __restrict__ W_in, const float* __restrict__ W_h,
    const float* __restrict__ bias, float* __restrict__ out) {
  __shared__ __align__(16) float h0[2 * HP];
  __shared__ __align__(16) float h1[2 * HP];

  const int b   = blockIdx.x;
  const int tid = threadIdx.x;          // 0..255
  const int p   = tid >> 1;             // output index 0..127
  const int i   = tid & 1;              // half 0..1 (pairs lane-aligned)

  // ---- this lane's weight slices (constant-indexed -> SROA) ----
  float wh[64];
#pragma unroll
  for (int m = 0; m < 64; ++m) wh[m] = W_h[(64 * i + m) * H_DIM + p];
  float wx[16];
#pragma unroll
  for (int m = 0; m < 16; ++m) wx[m] = W_in[(16 * i + m) * H_DIM + p];
  const float bj = bias[p];
  float hown = state[(size_t)b * H_DIM + p];  // true only on lane i==1

  if (tid < H_DIM)
    h0[HP * (tid >> 6) + (tid & 63)] = state[(size_t)b * H_DIM + tid];

  const int xs4 = B_DIM * D_DIM / 4;    // float4 stride per t
  // Pointer-carried addressing (no per-step 64-bit multiplies):
  const float4* xpf = reinterpret_cast<const float4*>(x + (size_t)b * D_DIM) + 4 * i;
  float* outp = out + (size_t)b * H_DIM + p;   // advances by BH per step

  // t=0 x quads, then xpf points at t=1.
  float4 xa0 = xpf[0], xa1 = xpf[1], xa2 = xpf[2], xa3 = xpf[3];
  float4 xb0, xb1, xb2, xb3;
  xpf += xs4;
  __syncthreads();

#define STEP(HRD, HWR, X0, X1, X2, X3) { \
    const float4* hb4 = reinterpret_cast<const float4*>(HRD); \
    float s1 = 0.f, s2 = 0.f; \
    _Pragma("unroll") \
    for (int r = 0; r < 2; ++r) { \
      /* s1 chunk first: 16 reg-only FMAs cover the h b128 read latency */ \
      s1 = fmaf(X0.x, wx[0],  s1); s1 = fmaf(X0.y, wx[1],  s1); \
      s1 = fmaf(X0.z, wx[2],  s1); s1 = fmaf(X0.w, wx[3],  s1); \
      s1 = fmaf(X1.x, wx[4],  s1); s1 = fmaf(X1.y, wx[5],  s1); \
      s1 = fmaf(X1.z, wx[6],  s1); s1 = fmaf(X1.w, wx[7],  s1); \
      s1 = fmaf(X2.x, wx[8],  s1); s1 = fmaf(X2.y, wx[9],  s1); \
      s1 = fmaf(X2.z, wx[10], s1); s1 = fmaf(X2.w, wx[11], s1); \
      s1 = fmaf(X3.x, wx[12], s1); s1 = fmaf(X3.y, wx[13], s1); \
      s1 = fmaf(X3.z, wx[14], s1); s1 = fmaf(X3.w, wx[15], s1); \
      _Pragma("unroll") \
      for (int m = 0; m < 16; ++m) { \
        float4 h4 = hb4[17 * i + m];    /* padded: bank-disjoint halves */ \
        s2 = fmaf(h4.x, wh[4 * m + 0], s2); \
        s2 = fmaf(h4.y, wh[4 * m + 1], s2); \
        s2 = fmaf(h4.z, wh[4 * m + 2], s2); \
        s2 = fmaf(h4.w, wh[4 * m + 3], s2); \
      } \
      if (r < 1) { s1 = dpp_shr1(s1); s2 = dpp_shr1(s2); } \
    } \
    float a  = __fadd_rn(__fadd_rn(s1, s2), bj); \
    float th = xla_tanh_fma_f32(a); \
    float hv = __fadd_rn(hown, th); \
    if (i == 1) (HWR)[HP * (p >> 6) + (p & 63)] = hv; \
    hown = hv;  /* only lane 1's is meaningful */ \
    __syncthreads(); \
    /* store AFTER barrier: vmcnt drain hides under the next step. */ \
    if (i == 1) *outp = hv; \
    outp += BH; \
  }

  for (int t = 0; t < T_DIM; t += 2) {
    // even step: prefetch t+1 quads, consume xa (h0 -> h1)
    xb0 = xpf[0]; xb1 = xpf[1]; xb2 = xpf[2]; xb3 = xpf[3];
    xpf += xs4;                          // -> t+2
    STEP(h0, h1, xa0, xa1, xa2, xa3)
    // odd step: prefetch t+2 quads (clamped at the tail), consume xb
    {
      const float4* xq = (t + 2 < T_DIM) ? xpf : (xpf - xs4);
      xa0 = xq[0]; xa1 = xq[1]; xa2 = xq[2]; xa3 = xq[3];
      xpf += xs4;                        // -> t+3
    }
    STEP(h1, h0, xb0, xb1, xb2, xb3)
  }

  // final_state = h after last step (== outputs[T-1]); outp now points at
  // out + T*BH + b*H + p exactly.
  if (i == 1) *outp = hown;
}

extern "C" void kernel_launch(void* const* d_in, const int* in_sizes, int n_in,
                              void* d_out, int out_size, void* d_ws, size_t ws_size,
                              hipStream_t stream) {
  const float* x     = (const float*)d_in[0];
  const float* state = (const float*)d_in[1];
  const float* W_in  = (const float*)d_in[2];
  const float* W_h   = (const float*)d_in[3];
  const float* bias  = (const float*)d_in[4];
  float* out = (float*)d_out;

  diffeq_kernel<<<B_DIM, 256, 0, stream>>>(x, state, W_in, W_h, bias, out);
}